// Round 20
// baseline (409.299 us; speedup 1.0000x reference)
//
#include <hip/hip_runtime.h>

// Problem: B=4, T=2048, C=512, H=8, D=64.
// Inputs/outputs fp32 (per reference dtypes); internal pipeline bf16.
typedef __bf16 bf16x8 __attribute__((ext_vector_type(8)));
typedef float f32x4 __attribute__((ext_vector_type(4)));
typedef unsigned short ushort8_t __attribute__((ext_vector_type(8)));
typedef unsigned short ushort4_t __attribute__((ext_vector_type(4)));

#define MFMA16(a, b, c) __builtin_amdgcn_mfma_f32_16x16x32_bf16(a, b, c, 0, 0, 0)
#define EXPC 0.18033688011112042f   // log2(e)/8 :  exp(att) = exp2(acc * EXPC)
#define EXP2(x) __builtin_amdgcn_exp2f(x)

__device__ __forceinline__ float bf2f(unsigned short u) {
    union { unsigned int i; float f; } c; c.i = ((unsigned int)u) << 16; return c.f;
}
// native HW convert (RNE)
__device__ __forceinline__ unsigned short f2bf(float f) {
    union { __bf16 h; unsigned short u; } c; c.h = (__bf16)f; return c.u;
}
__device__ __forceinline__ unsigned int pk2(float lo, float hi) {
    return (unsigned int)f2bf(lo) | ((unsigned int)f2bf(hi) << 16);
}
// packed bf16x2 global atomic add (gfx942+/gfx950)
__device__ __forceinline__ void atom_pk(unsigned short* a, unsigned int v) {
    asm volatile("global_atomic_pk_add_bf16 %0, %1, off" :: "v"(a), "v"(v) : "memory");
}

// ---------------------------------------------------------------- W = qkv + delta (fp32 in -> bf16 W, W^T); also zero the sums accumulator
__global__ void prep_w(const float* __restrict__ qkv,
                       const float* __restrict__ delta,
                       unsigned short* __restrict__ W,
                       unsigned short* __restrict__ WT,
                       float* __restrict__ sums) {
    __shared__ __align__(16) unsigned short tile[64][72];
    const int r0 = blockIdx.x * 64, c0 = blockIdx.y * 64;
    // zero sums[32][2048] (65536 floats): 64 blocks x 256 threads x 1 float4
    {
        const int lin = (blockIdx.y * 8 + blockIdx.x) * 256 + threadIdx.x;
        float4 z = {0.f, 0.f, 0.f, 0.f};
        *(float4*)(sums + (size_t)lin * 4) = z;
    }
    const int rl = threadIdx.x >> 2;
    const int cg = (threadIdx.x & 3) * 16;
    const size_t idx = (size_t)(r0 + rl) * 512 + c0 + cg;
    ushort8_t o0, o1;
    for (int j = 0; j < 8; ++j) {
        o0[j] = f2bf(qkv[idx + j] + delta[idx + j]);
        o1[j] = f2bf(qkv[idx + 8 + j] + delta[idx + 8 + j]);
        tile[rl][cg + j] = o0[j];
        tile[rl][cg + 8 + j] = o1[j];
    }
    *(ushort8_t*)(W + idx) = o0;
    *(ushort8_t*)(W + idx + 8) = o1;
    __syncthreads();
    const int cl = threadIdx.x >> 2;
    const int rg = (threadIdx.x & 3) * 16;
    ushort8_t t0, t1;
    for (int j = 0; j < 8; ++j) {
        t0[j] = tile[rg + j][cl];
        t1[j] = tile[rg + 8 + j][cl];
    }
    const size_t tidx = (size_t)(c0 + cl) * 512 + r0 + rg;
    *(ushort8_t*)(WT + tidx) = t0;
    *(ushort8_t*)(WT + tidx + 8) = t1;
}

// ---------------------------------------------------------------- C[m,n] = sum_k A[m,k]*B[n,k]
__global__ __launch_bounds__(256) void gemm_bt(const void* __restrict__ Ap,
                                               const unsigned short* __restrict__ Bm,
                                               void* __restrict__ Cp,
                                               int M, int N, int K, int mode, int aF32) {
    __shared__ __align__(16) unsigned short As[64][40];
    __shared__ __align__(16) unsigned short Bs[64][40];
    const int tid = threadIdx.x;
    const int wid = tid >> 6, lane = tid & 63;
    const int quad = lane >> 4, l16 = lane & 15;
    const int m0 = blockIdx.x * 64, n0 = blockIdx.y * 64;
    const int waveM = (wid & 1) * 32, waveN = (wid >> 1) * 32;
    const int ldRow = tid >> 2;
    const int ldCol = (tid & 3) * 8;
    f32x4 acc[2][2] = {};
    for (int k0 = 0; k0 < K; k0 += 32) {
        ushort8_t av;
        if (aF32) {
            const float* Af = (const float*)Ap + (size_t)(m0 + ldRow) * K + k0 + ldCol;
            float4 f0 = *(const float4*)(Af);
            float4 f1 = *(const float4*)(Af + 4);
            av[0] = f2bf(f0.x); av[1] = f2bf(f0.y); av[2] = f2bf(f0.z); av[3] = f2bf(f0.w);
            av[4] = f2bf(f1.x); av[5] = f2bf(f1.y); av[6] = f2bf(f1.z); av[7] = f2bf(f1.w);
        } else {
            av = *(const ushort8_t*)((const unsigned short*)Ap + (size_t)(m0 + ldRow) * K + k0 + ldCol);
        }
        ushort8_t bv = *(const ushort8_t*)(Bm + (size_t)(n0 + ldRow) * K + k0 + ldCol);
        __syncthreads();
        *(ushort8_t*)(&As[ldRow][ldCol]) = av;
        *(ushort8_t*)(&Bs[ldRow][ldCol]) = bv;
        __syncthreads();
        bf16x8 a[2], b[2];
        a[0] = *(const bf16x8*)(&As[waveM + l16][quad * 8]);
        a[1] = *(const bf16x8*)(&As[waveM + 16 + l16][quad * 8]);
        b[0] = *(const bf16x8*)(&Bs[waveN + l16][quad * 8]);
        b[1] = *(const bf16x8*)(&Bs[waveN + 16 + l16][quad * 8]);
        for (int mt = 0; mt < 2; ++mt)
            for (int nt = 0; nt < 2; ++nt)
                acc[mt][nt] = MFMA16(a[mt], b[nt], acc[mt][nt]);
    }
    for (int mt = 0; mt < 2; ++mt)
        for (int nt = 0; nt < 2; ++nt)
            for (int r = 0; r < 4; ++r) {
                int gm = m0 + waveM + mt * 16 + quad * 4 + r;   // C/D: row = quad*4+reg
                int gn = n0 + waveN + nt * 16 + l16;            //       col = lane&15
                float v = acc[mt][nt][r];
                if (mode == 0) {
                    ((float*)Cp)[(size_t)gm * N + gn] = v;
                } else {
                    size_t oidx = ((size_t)((gm >> 11) * 8 + (gn >> 6)) * 2048 + (gm & 2047)) * 64 + (gn & 63);
                    ((unsigned short*)Cp)[oidx] = f2bf(v);
                }
            }
}

// ---------------------------------------------------------------- RMSNorm: n1,n2 (bh,t,d) bf16; n3 transposed (bh,d,t) bf16
__global__ void rms_prepare(const unsigned short* __restrict__ w,
                            const float* __restrict__ g1,
                            const float* __restrict__ g2,
                            const float* __restrict__ g3,
                            unsigned short* __restrict__ n1,
                            unsigned short* __restrict__ n2,
                            unsigned short* __restrict__ n3t) {
    __shared__ __align__(16) unsigned short tile[64][72];
    const int bh = blockIdx.y;
    const int t0 = blockIdx.x * 64;
    const int tl = threadIdx.x >> 2;
    const int dg = (threadIdx.x & 3) * 16;
    const size_t rowbase = ((size_t)bh * 2048 + t0 + tl) * 64;
    ushort8_t w0 = *(const ushort8_t*)(w + rowbase + dg);
    ushort8_t w1 = *(const ushort8_t*)(w + rowbase + dg + 8);
    float v[16];
    for (int j = 0; j < 8; ++j) { v[j] = bf2f(w0[j]); v[8 + j] = bf2f(w1[j]); }
    float ss = 0.f;
    for (int j = 0; j < 16; ++j) ss += v[j] * v[j];
    ss += __shfl_xor(ss, 1);
    ss += __shfl_xor(ss, 2);                       // 4 lanes per row share the sum
    const float inv = rsqrtf(ss * (1.0f / 64.0f) + 1.1920929e-07f);
    ushort8_t a0, a1, b0, b1;
    for (int j = 0; j < 16; ++j) {
        int d = dg + j;
        float nb = v[j] * inv;
        unsigned short x1 = f2bf(nb * g1[d]);
        unsigned short x2 = f2bf(nb * g2[d]);
        unsigned short x3 = f2bf(nb * g3[d]);
        if (j < 8) { a0[j] = x1; b0[j] = x2; } else { a1[j - 8] = x1; b1[j - 8] = x2; }
        tile[tl][d] = x3;
    }
    *(ushort8_t*)(n1 + rowbase + dg) = a0;
    *(ushort8_t*)(n1 + rowbase + dg + 8) = a1;
    *(ushort8_t*)(n2 + rowbase + dg) = b0;
    *(ushort8_t*)(n2 + rowbase + dg + 8) = b1;
    __syncthreads();
    const int dr = threadIdx.x >> 2;
    const int tg = (threadIdx.x & 3) * 16;
    ushort8_t o0, o1;
    for (int j = 0; j < 8; ++j) {
        o0[j] = tile[tg + j][dr];
        o1[j] = tile[tg + 8 + j][dr];
    }
    const size_t obase = ((size_t)bh * 64 + dr) * 2048 + t0 + tg;
    *(ushort8_t*)(n3t + obase) = o0;
    *(ushort8_t*)(n3t + obase + 8) = o1;
}

// ---------------------------------------------------------------- s = row sums of exp(att) (== col sums: att SYMMETRIC). (R17, measured-good)
__global__ __launch_bounds__(512) void att_sums_tri(const unsigned short* __restrict__ n1,
                                                    const unsigned short* __restrict__ n2,
                                                    float* __restrict__ sums) {
    __shared__ __align__(16) unsigned short Kbuf[128][64];   // chunk-swizzled rows (16 KB)
    __shared__ float colAcc[128];
    const int bh = blockIdx.y;
    const int tid = threadIdx.x;
    const int lane = tid & 63, wid = tid >> 6;
    const int quad = lane >> 4, l16 = lane & 15;
    // decode upper-triangle pair (bi <= bj) from blockIdx.x in [0,136)
    int rem = blockIdx.x, bi = 0;
    while (rem >= 16 - bi) { rem -= 16 - bi; ++bi; }
    const int bj = bi + rem;
    const int diag = (bi == bj);
    if (tid < 128) colAcc[tid] = 0.f;
    const size_t base = (size_t)bh * 2048 * 64;
    const int r0 = bi * 128 + wid * 16;
    const unsigned short* Ar = n1 + base + (size_t)(r0 + l16) * 64 + quad * 8;
    bf16x8 a0 = *(const bf16x8*)(Ar);
    bf16x8 a1 = *(const bf16x8*)(Ar + 32);
    const int srow = tid >> 3, schunk = tid & 7;
    const int swslot = (schunk ^ (srow & 7)) * 8;
    const unsigned short* gK = n2 + base + (size_t)(bj * 128 + srow) * 64 + schunk * 8;
    ushort8_t k0 = *(const ushort8_t*)(gK);
    ushort8_t k1 = *(const ushort8_t*)(gK + 64 * 64);
    *(ushort8_t*)(&Kbuf[srow][swslot]) = k0;
    *(ushort8_t*)(&Kbuf[64 + srow][swslot]) = k1;   // (srow+64)&7 == srow&7
    __syncthreads();
    float rsum[4] = {};
    const int pK0 = (quad ^ (l16 & 7)) * 8;
    const int pK1 = ((quad + 4) ^ (l16 & 7)) * 8;
    for (int g8 = 0; g8 < 8; ++g8) {
        const int row = g8 * 16 + l16;
        bf16x8 b0 = *(const bf16x8*)(&Kbuf[row][pK0]);
        bf16x8 b1 = *(const bf16x8*)(&Kbuf[row][pK1]);
        f32x4 acc = {0.f, 0.f, 0.f, 0.f};
        acc = MFMA16(a0, b0, acc);
        acc = MFMA16(a1, b1, acc);
        float ce = 0.f;
        for (int r = 0; r < 4; ++r) {
            float E = EXP2(acc[r] * EXPC);
            rsum[r] += E;
            ce += E;
        }
        ce += __shfl_xor(ce, 16);
        ce += __shfl_xor(ce, 32);
        if (lane < 16) atomicAdd(&colAcc[g8 * 16 + l16], ce);
    }
    for (int r = 0; r < 4; ++r) {
        float s = rsum[r];
        s += __shfl_xor(s, 1); s += __shfl_xor(s, 2);
        s += __shfl_xor(s, 4); s += __shfl_xor(s, 8);
        if (l16 == 0)
            atomicAdd(&sums[(size_t)bh * 2048 + r0 + quad * 4 + r], s);
    }
    __syncthreads();
    if (!diag && tid < 128)
        atomicAdd(&sums[(size_t)bh * 2048 + bj * 128 + tid], colAcc[tid]);
}

// ---------------------------------------------------------------- sRinv = 1/sums
__global__ void recip(const float* __restrict__ sums, float* __restrict__ sRinv) {
    const int i = blockIdx.x * 256 + threadIdx.x;
    sRinv[i] = 1.0f / sums[i];
}

// ---------------------------------------------------------------- y += score @ n3 via TRIANGLE symmetry (R19).
// P = exp(att)*(s_i+s_j) is symmetric.  Circulant pairs: block bi handles
// bj=(bi+d)&15 for d=0..7 (+d=8 if bi<8) -> 136 tiles, balanced.  Per pair:
// swapped QK -> P[i][j] (b64, chunk^i swizzle) + reg copy; y[bi] += P*V_bj (regs,
// exact fp32 across all pairs); PT[j][i] rewritten from regs; y[bj] += PT*V_bi
// -> global packed-bf16 atomics.  Vbi lives in Kb's region (Kb dead post-QK).
// LDS = 16K (Kb/Vbi) + 16K (Vbj) + 32K (P/PT) = 64KB -> 2 blocks/CU.
__global__ __launch_bounds__(512) void att_apply_tri(const unsigned short* __restrict__ n1,
                                                     const unsigned short* __restrict__ n2,
                                                     const unsigned short* __restrict__ n3t,
                                                     const float* __restrict__ sRinv,
                                                     unsigned short* __restrict__ ybuf) {
    __shared__ __align__(16) char smem[65536];
    unsigned short* Kb  = (unsigned short*)smem;            // [128][64] rows swz (then Vbi [64][128])
    unsigned short* Vbj = (unsigned short*)(smem + 16384);  // [64][128] chunk^(d&15)
    unsigned short* Pb  = (unsigned short*)(smem + 32768);  // [128][128] chunk-swz (P then PT)
    const int bh = blockIdx.y, bi = blockIdx.x;
    const int bb = bh >> 3, hh = bh & 7;
    const int tid = threadIdx.x;
    const int lane = tid & 63, wid = tid >> 6;
    const int quad = lane >> 4, l16 = lane & 15;
    const size_t sbase = (size_t)bh * 2048;
    const size_t base = sbase * 64;
    const unsigned short* n3b = n3t + (size_t)bh * 64 * 2048;
    // own-row A frags + s_i
    const int myrow = bi * 128 + wid * 16 + l16;
    const unsigned short* Ar = n1 + base + (size_t)myrow * 64 + quad * 8;
    bf16x8 a0 = *(const bf16x8*)(Ar);
    bf16x8 a1 = *(const bf16x8*)(Ar + 32);
    const float rr = sRinv[sbase + myrow];
    // Vbi (V^T cols of own tile) held in regs; re-staged into Kb region each pair
    const int sd = tid >> 3, sc = tid & 7;          // staging: d-row / chunk
    ushort8_t vbi0, vbi1;
    {
        const unsigned short* gVi = n3b + (size_t)sd * 2048 + bi * 128 + sc * 8;
        vbi0 = *(const ushort8_t*)(gVi);
        vbi1 = *(const ushort8_t*)(gVi + 64);
    }
    f32x4 yacc[4] = {};
    const int npair = (bi < 8) ? 9 : 8;
    for (int pp = 0; pp < npair; ++pp) {
        const int bj = (bi + pp) & 15;
        const int diag = (pp == 0);
        // issue next tiles' global loads (T14)
        const unsigned short* gK = n2 + base + (size_t)(bj * 128 + sd) * 64 + sc * 8;
        ushort8_t k0 = *(const ushort8_t*)(gK);
        ushort8_t k1 = *(const ushort8_t*)(gK + 64 * 64);
        const unsigned short* gV = n3b + (size_t)sd * 2048 + bj * 128 + sc * 8;
        ushort8_t v0 = *(const ushort8_t*)(gV);
        ushort8_t v1 = *(const ushort8_t*)(gV + 64);
        __syncthreads();   // A: prev pair's consumers done
        // Kb: rows bj*128.. (row-chunk swz, att_sums_tri pattern)
        *(ushort8_t*)(Kb + sd * 64 + ((sc ^ (sd & 7)) * 8)) = k0;
        *(ushort8_t*)(Kb + (64 + sd) * 64 + ((sc ^ (sd & 7)) * 8)) = k1;
        // Vbj: [64 d][128 cols] chunk^(d&15)
        *(ushort8_t*)(Vbj + sd * 128 + ((sc ^ (sd & 15)) & 15) * 8) = v0;
        *(ushort8_t*)(Vbj + sd * 128 + (((sc + 8) ^ (sd & 15)) & 15) * 8) = v1;
        __syncthreads();   // B: staging visible
        // QK (swapped): acc[r] = att[j = jgrp*16+quad*4+r][i = myrow]; P write + reg copy
        ushort4_t pkreg[8];
        const int pK0 = (quad ^ (l16 & 7)) * 8;
        const int pK1 = ((quad + 4) ^ (l16 & 7)) * 8;
#pragma unroll
        for (int jgrp = 0; jgrp < 8; ++jgrp) {
            const int jr = jgrp * 16 + l16;
            bf16x8 b0 = *(const bf16x8*)(Kb + jr * 64 + pK0);
            bf16x8 b1 = *(const bf16x8*)(Kb + jr * 64 + pK1);
            const f32x4 cv = *(const f32x4*)(sRinv + sbase + bj * 128 + jgrp * 16 + quad * 4);
            f32x4 acc = {0.f, 0.f, 0.f, 0.f};
            acc = MFMA16(b0, a0, acc);
            acc = MFMA16(b1, a1, acc);
            ushort4_t pk;
            for (int r = 0; r < 4; ++r)
                pk[r] = f2bf(EXP2(acc[r] * EXPC) * (rr + cv[r]));
            pkreg[jgrp] = pk;
            // P[i = wid*16+l16][j]: chunk = jgrp*2+(quad>>1), slot = chunk^l16, half (quad&1)
            *(ushort4_t*)(Pb + (wid * 16 + l16) * 128 +
                          ((jgrp * 2 + (quad >> 1)) ^ l16) * 8 + (quad & 1) * 4) = pk;
        }
        __syncthreads();   // C: P visible; Kb reads done -> Vbi restage OK
        // Vbi into Kb region (same layout as Vbj)
        *(ushort8_t*)(Kb + sd * 128 + ((sc ^ (sd & 15)) & 15) * 8) = vbi0;
        *(ushort8_t*)(Kb + sd * 128 + (((sc + 8) ^ (sd & 15)) & 15) * 8) = vbi1;
        // y[bi] PV: D[m=d][n=i=myrow] += Vbj^T-frag x P-frag
#pragma unroll
        for (int jc = 0; jc < 4; ++jc) {
            bf16x8 pf = *(const bf16x8*)(Pb + (wid * 16 + l16) * 128 + (((jc * 4 + quad) ^ l16) * 8));
#pragma unroll
            for (int dt = 0; dt < 4; ++dt) {
                bf16x8 af = *(const bf16x8*)(Vbj + (dt * 16 + l16) * 128 + (((jc * 4 + quad) ^ l16) * 8));
                yacc[dt] = MFMA16(af, pf, yacc[dt]);
            }
        }
        __syncthreads();   // D: PV's P reads done; Vbi visible
        if (!diag) {
            // PT[j][i] from regs: slot = (wid*2 + l16>>3) ^ (j&15)
            const int ich = wid * 2 + (l16 >> 3);
#pragma unroll
            for (int jgrp = 0; jgrp < 8; ++jgrp)
#pragma unroll
                for (int r = 0; r < 4; ++r) {
                    const int j = jgrp * 16 + quad * 4 + r;
                    Pb[j * 128 + ((ich ^ (quad * 4 + r)) * 8) + (l16 & 7)] = pkreg[jgrp][r];
                }
        }
        __syncthreads();   // E: PT visible
        if (!diag) {
            // y[bj] = PT x Vbi: D[m=d][n=j = bj*128 + wid*16 + l16]
            f32x4 ybj[4] = {};
#pragma unroll
            for (int ic = 0; ic < 4; ++ic) {
                bf16x8 ptf = *(const bf16x8*)(Pb + (wid * 16 + l16) * 128 + (((ic * 4 + quad) ^ l16) * 8));
#pragma unroll
                for (int dt = 0; dt < 4; ++dt) {
                    bf16x8 af2 = *(const bf16x8*)(Kb + (dt * 16 + l16) * 128 + (((ic * 4 + quad) ^ l16) * 8));
                    ybj[dt] = MFMA16(af2, ptf, ybj[dt]);
                }
            }
            const int tj = bj * 128 + wid * 16 + l16;
            unsigned short* yb0 = ybuf + ((size_t)(bb * 2048 + tj) * 512) + hh * 64;
#pragma unroll
            for (int dt = 0; dt < 4; ++dt) {
                const int d0 = dt * 16 + quad * 4;
                atom_pk(yb0 + d0, pk2(ybj[dt][0], ybj[dt][1]));
                atom_pk(yb0 + d0 + 2, pk2(ybj[dt][2], ybj[dt][3]));
            }
        }
    }
    // final dump of register-accumulated y[bi]
    const int ti = bi * 128 + wid * 16 + l16;
    unsigned short* yb0 = ybuf + ((size_t)(bb * 2048 + ti) * 512) + hh * 64;
#pragma unroll
    for (int dt = 0; dt < 4; ++dt) {
        const int d0 = dt * 16 + quad * 4;
        atom_pk(yb0 + d0, pk2(yacc[dt][0], yacc[dt][1]));
        atom_pk(yb0 + d0 + 2, pk2(yacc[dt][2], yacc[dt][3]));
    }
}

extern "C" void kernel_launch(void* const* d_in, const int* in_sizes, int n_in,
                              void* d_out, int out_size, void* d_ws, size_t ws_size,
                              hipStream_t stream) {
    const float* x   = (const float*)d_in[0];
    const float* dlt = (const float*)d_in[1];
    const float* qkv = (const float*)d_in[2];
    const float* g1  = (const float*)d_in[3];
    const float* g2  = (const float*)d_in[4];
    const float* g3  = (const float*)d_in[5];
    float* out = (float*)d_out;
    char* ws = (char*)d_ws;
    // workspace: W/WT | wb(->yb) | n1 | n2 | n3t | sums | sRinv  (as R17)
    unsigned short* W   = (unsigned short*)(ws);
    unsigned short* WT  = (unsigned short*)(ws + 524288);
    unsigned short* wb  = (unsigned short*)(ws + 1048576);
    unsigned short* yb  = wb;
    unsigned short* n1  = (unsigned short*)(ws + 9437184);
    unsigned short* n2  = (unsigned short*)(ws + 17825792);
    unsigned short* n3t = (unsigned short*)(ws + 26214400);
    float* sums  = (float*)(ws + 34603008);
    float* sRinv = (float*)(ws + 34865152);

    prep_w<<<dim3(8, 8), 256, 0, stream>>>(qkv, dlt, W, WT, sums);
    gemm_bt<<<dim3(128, 8), 256, 0, stream>>>(x, W, wb, 8192, 512, 512, 1, 1);
    rms_prepare<<<dim3(32, 32), 256, 0, stream>>>(wb, g1, g2, g3, n1, n2, n3t);
    hipMemsetAsync(yb, 0, 8388608, stream);   // zero y accumulator (wb dead after rms)
    att_sums_tri<<<dim3(136, 32), 512, 0, stream>>>(n1, n2, sums);
    recip<<<256, 256, 0, stream>>>(sums, sRinv);
    att_apply_tri<<<dim3(16, 32), 512, 0, stream>>>(n1, n2, n3t, sRinv, yb);
    gemm_bt<<<dim3(128, 8), 256, 0, stream>>>(yb, WT, out, 8192, 512, 512, 0, 0);
}